// Round 3
// baseline (1854.875 us; speedup 1.0000x reference)
//
#include <hip/hip_runtime.h>
#include <math.h>

// Problem constants
#define T_TOKENS 32768
#define DIM      2048
#define NEXP     256
#define NGROUP   8
#define TOPG     4
#define TOPK     8
#define SCALE    2.5

// Tiling
#define BM 64
#define BK 32
#define NKT (DIM / BK)
// LDS strides in floats
#define AS_STRIDE 68     // 64 + 4
#define BS_STRIDE 260    // 256 + 4

__global__ __launch_bounds__(256, 2) void nemotron_router_kernel(
    const float* __restrict__ H,     // [T, D] fp32
    const float* __restrict__ Wt,    // [E, D] fp32
    const float* __restrict__ bias,  // [E]    fp32
    float* __restrict__ out)         // [T*8 idx as float][T*8 weights]
{
    __shared__ __align__(16) float As[BK * AS_STRIDE];   //  8704 B
    __shared__ __align__(16) float Bs[BK * BS_STRIDE];   // 33280 B
    __shared__ double biasD[NEXP];                       //  2048 B

    const int tid  = threadIdx.x;
    const int lane = tid & 63;
    const int wid  = tid >> 6;           // wave id 0..3
    const int t0   = blockIdx.x * BM;

    biasD[tid] = (double)bias[tid];

    // micro-tile: wave `wid` owns token rows r0..r0+15; lane owns experts e0..e0+3
    const int r0 = wid * 16;
    const int e0 = lane * 4;

    // staging mapping
    const int arow = tid >> 2;           // 0..63
    const int acol = (tid & 3) * 8;      // 0,8,16,24
    const float* Aptr = H + (size_t)(t0 + arow) * DIM + acol;
    const float* Bptr = Wt + (size_t)tid * DIM;   // expert == tid

    double acc[16][4];
    #pragma unroll
    for (int i = 0; i < 16; ++i)
        #pragma unroll
        for (int j = 0; j < 4; ++j)
            acc[i][j] = 0.0;

    // prefetch tile 0
    float4 ra0 = *(const float4*)(Aptr + 0);
    float4 ra1 = *(const float4*)(Aptr + 4);
    float4 rb[8];
    #pragma unroll
    for (int q = 0; q < 8; ++q) rb[q] = *(const float4*)(Bptr + q * 4);

    for (int kt = 0; kt < NKT; ++kt) {
        __syncthreads();   // previous tile's LDS reads complete

        // staged registers -> LDS (fp32, k-major)
        {
            const float a[8] = {ra0.x, ra0.y, ra0.z, ra0.w, ra1.x, ra1.y, ra1.z, ra1.w};
            #pragma unroll
            for (int m = 0; m < 8; ++m)
                As[(acol + m) * AS_STRIDE + arow] = a[m];
        }
        #pragma unroll
        for (int q = 0; q < 8; ++q) {
            Bs[(q * 4 + 0) * BS_STRIDE + tid] = rb[q].x;
            Bs[(q * 4 + 1) * BS_STRIDE + tid] = rb[q].y;
            Bs[(q * 4 + 2) * BS_STRIDE + tid] = rb[q].z;
            Bs[(q * 4 + 3) * BS_STRIDE + tid] = rb[q].w;
        }
        __syncthreads();

        // prefetch next tile (overlaps with compute)
        if (kt + 1 < NKT) {
            const int k1 = (kt + 1) * BK;
            ra0 = *(const float4*)(Aptr + k1);
            ra1 = *(const float4*)(Aptr + k1 + 4);
            #pragma unroll
            for (int q = 0; q < 8; ++q) rb[q] = *(const float4*)(Bptr + k1 + q * 4);
        }

        // fp64 compute, fp32 operands cvt'd at use
        #pragma unroll 2
        for (int kk = 0; kk < BK; ++kk) {
            const float4 bvf = *(const float4*)&Bs[kk * BS_STRIDE + e0];   // linear b128
            const double b0 = (double)bvf.x, b1 = (double)bvf.y;
            const double b2 = (double)bvf.z, b3 = (double)bvf.w;
            #pragma unroll
            for (int m = 0; m < 4; ++m) {
                const float4 avf = *(const float4*)&As[kk * AS_STRIDE + r0 + 4 * m]; // broadcast
                const float af[4] = {avf.x, avf.y, avf.z, avf.w};
                #pragma unroll
                for (int q = 0; q < 4; ++q) {
                    const double a = (double)af[q];
                    const int i = m * 4 + q;
                    acc[i][0] = fma(a, b0, acc[i][0]);
                    acc[i][1] = fma(a, b1, acc[i][1]);
                    acc[i][2] = fma(a, b2, acc[i][2]);
                    acc[i][3] = fma(a, b3, acc[i][3]);
                }
            }
        }
    }

    // ---- routing: wave-parallel, all decisions fp64 ----
    const int gm = lane >> 3;   // my experts' group (e0..e0+3 all inside group lane>>3)
    double bj[4];
    #pragma unroll
    for (int j = 0; j < 4; ++j) bj[j] = biasD[e0 + j];

    // logits -> biased sigmoid values (in place)
    #pragma unroll
    for (int i = 0; i < 16; ++i)
        #pragma unroll
        for (int j = 0; j < 4; ++j)
            acc[i][j] = 1.0 / (1.0 + exp(-acc[i][j])) + bj[j];

    #pragma unroll
    for (int i = 0; i < 16; ++i) {
        // --- group top-2 (values only; sum is order-symmetric w/ descending add) ---
        double m1 = acc[i][0], m2 = -1e300;
        #pragma unroll
        for (int j = 1; j < 4; ++j) {
            const double v = acc[i][j];
            if (v > m1) { m2 = m1; m1 = v; }
            else if (v > m2) { m2 = v; }
        }
        #pragma unroll
        for (int mask = 1; mask <= 4; mask <<= 1) {   // merge across 8-lane group cluster
            const double o1 = __shfl_xor(m1, mask);
            const double o2 = __shfl_xor(m2, mask);
            const double lo = fmin(m1, o1);
            m1 = fmax(m1, o1);
            m2 = fmax(lo, fmax(m2, o2));
        }
        const double gsm = m1 + m2;

        // gather all 8 group scores (uniform src lanes)
        double gs[NGROUP];
        #pragma unroll
        for (int g = 0; g < NGROUP; ++g) gs[g] = __shfl(gsm, g * 8);

        // --- top-4 groups (ties -> lower index) ---
        unsigned gsel = 0;
        #pragma unroll
        for (int g = 0; g < NGROUP; ++g) {
            int rank = 0;
            #pragma unroll
            for (int h = 0; h < NGROUP; ++h)
                rank += (gs[h] > gs[g]) || (gs[h] == gs[g] && h < g);
            if (rank < TOPG) gsel |= 1u << g;
        }
        const bool allowed = (gsel >> gm) & 1u;

        // --- top-8 experts, descending, ties -> lower index ---
        double wk[TOPK];
        int    ik[TOPK];
        double wsum = 0.0;
        #pragma unroll
        for (int k = 0; k < TOPK; ++k) {
            double bv = -1e300;
            int    be = 1 << 30;
            if (allowed) {
                #pragma unroll
                for (int j = 0; j < 4; ++j) {
                    if (acc[i][j] > bv) { bv = acc[i][j]; be = e0 + j; }
                }
            }
            #pragma unroll
            for (int mask = 1; mask <= 32; mask <<= 1) {
                const double ov = __shfl_xor(bv, mask);
                const int    oe = __shfl_xor(be, mask);
                if (ov > bv || (ov == bv && oe < be)) { bv = ov; be = oe; }
            }
            const double w = bv - biasD[be];   // un-biased sigmoid
            wk[k] = w;
            ik[k] = be;
            wsum += w;
            const bool own = ((be >> 2) == lane);
            #pragma unroll
            for (int j = 0; j < 4; ++j)
                if (own && (be & 3) == j) acc[i][j] = -1e300;
        }

        if (lane == 0) {
            const double norm = SCALE / wsum;
            const size_t t = (size_t)(t0 + r0 + i);
            float* oi = out + t * TOPK;
            float* ow = out + (size_t)T_TOKENS * TOPK + t * TOPK;
            #pragma unroll
            for (int k = 0; k < TOPK; ++k) {
                oi[k] = (float)ik[k];
                ow[k] = (float)(wk[k] * norm);
            }
        }
    }
}

extern "C" void kernel_launch(void* const* d_in, const int* in_sizes, int n_in,
                              void* d_out, int out_size, void* d_ws, size_t ws_size,
                              hipStream_t stream) {
    const float* H    = (const float*)d_in[0];  // [32768, 2048]
    const float* Wt   = (const float*)d_in[1];  // [256, 2048]
    const float* bias = (const float*)d_in[2];  // [256]
    float* out = (float*)d_out;

    dim3 grid(T_TOKENS / BM);   // 512
    dim3 block(256);
    nemotron_router_kernel<<<grid, block, 0, stream>>>(H, Wt, bias, out);
}

// Round 4
// 878.755 us; speedup vs baseline: 2.1108x; 2.1108x over previous
//
#include <hip/hip_runtime.h>
#include <math.h>

// Problem constants
#define T_TOKENS 32768
#define DIM      2048
#define NEXP     256
#define NGROUP   8
#define GSIZE    32
#define TOPG     4
#define TOPK     8
#define SCALE    2.5
#define TAU      5e-5f     // rescue margin (biased-sigmoid units); fp32 err <~5e-7

// Main-pass tiling
#define BM 64
#define BK 32
#define NKT (DIM / BK)
#define AS_STRIDE 68       // 64 + 4 (floats)
#define BS_STRIDE 260      // 256 + 4
#define SC_STRIDE 257

#define RLIST_OFF 16       // rescue list offset in d_ws (ints); [0] = counter

// ---------------------------------------------------------------- init ----
__global__ void zero_counter(int* ws) {
    if (threadIdx.x == 0) ws[0] = 0;
}

// ---------------------------------------------------------------- main ----
__global__ __launch_bounds__(256, 2) void router_main(
    const float* __restrict__ H,     // [T, D]
    const float* __restrict__ Wt,    // [E, D]
    const float* __restrict__ bias,  // [E]
    float* __restrict__ out,         // [T*8 idx][T*8 weights]
    int* __restrict__ ws)            // rescue counter + list
{
    // union: {As [BK][AS_STRIDE], Bs [BK][BS_STRIDE]} (10496 f) / Sc [BM][SC_STRIDE] (16448 f)
    __shared__ __align__(16) float smem[BM * SC_STRIDE];   // 65792 B
    __shared__ float biasS[NEXP];

    float* As = smem;
    float* Bs = smem + BK * AS_STRIDE;
    float* Sc = smem;

    const int tid = threadIdx.x;
    const int t0  = blockIdx.x * BM;

    biasS[tid] = bias[tid];

    const int tc = tid & 31;
    const int tr = tid >> 5;
    const int r0 = tr * 8;
    const int c0 = tc * 8;

    float accT[8][8];   // running total
    #pragma unroll
    for (int i = 0; i < 8; ++i)
        #pragma unroll
        for (int j = 0; j < 8; ++j)
            accT[i][j] = 0.0f;

    const int arow = tid >> 2;
    const int acol = (tid & 3) * 8;
    const float* Aptr = H + (size_t)(t0 + arow) * DIM + acol;
    const float* Bptr = Wt + (size_t)tid * DIM;

    // prefetch tile 0
    float4 ra0 = *(const float4*)(Aptr + 0);
    float4 ra1 = *(const float4*)(Aptr + 4);
    float4 rb[8];
    #pragma unroll
    for (int q = 0; q < 8; ++q) rb[q] = *(const float4*)(Bptr + q * 4);

    for (int kt = 0; kt < NKT; ++kt) {
        __syncthreads();

        {
            const float a[8] = {ra0.x, ra0.y, ra0.z, ra0.w, ra1.x, ra1.y, ra1.z, ra1.w};
            #pragma unroll
            for (int m = 0; m < 8; ++m)
                As[(acol + m) * AS_STRIDE + arow] = a[m];
        }
        #pragma unroll
        for (int q = 0; q < 8; ++q) {
            Bs[(q * 4 + 0) * BS_STRIDE + tid] = rb[q].x;
            Bs[(q * 4 + 1) * BS_STRIDE + tid] = rb[q].y;
            Bs[(q * 4 + 2) * BS_STRIDE + tid] = rb[q].z;
            Bs[(q * 4 + 3) * BS_STRIDE + tid] = rb[q].w;
        }
        __syncthreads();

        if (kt + 1 < NKT) {
            const int k1 = (kt + 1) * BK;
            ra0 = *(const float4*)(Aptr + k1);
            ra1 = *(const float4*)(Aptr + k1 + 4);
            #pragma unroll
            for (int q = 0; q < 8; ++q) rb[q] = *(const float4*)(Bptr + k1 + q * 4);
        }

        // chunk accumulator (reduces sequential fp32 error ~5x)
        float accC[8][8];
        #pragma unroll
        for (int i = 0; i < 8; ++i)
            #pragma unroll
            for (int j = 0; j < 8; ++j)
                accC[i][j] = 0.0f;

        #pragma unroll 4
        for (int kk = 0; kk < BK; ++kk) {
            const float4 a0 = *(const float4*)&As[kk * AS_STRIDE + r0];
            const float4 a1 = *(const float4*)&As[kk * AS_STRIDE + r0 + 4];
            const float4 b0 = *(const float4*)&Bs[kk * BS_STRIDE + c0];
            const float4 b1 = *(const float4*)&Bs[kk * BS_STRIDE + c0 + 4];
            const float a[8] = {a0.x, a0.y, a0.z, a0.w, a1.x, a1.y, a1.z, a1.w};
            const float b[8] = {b0.x, b0.y, b0.z, b0.w, b1.x, b1.y, b1.z, b1.w};
            #pragma unroll
            for (int i = 0; i < 8; ++i)
                #pragma unroll
                for (int j = 0; j < 8; ++j)
                    accC[i][j] = fmaf(a[i], b[j], accC[i][j]);
        }

        #pragma unroll
        for (int i = 0; i < 8; ++i)
            #pragma unroll
            for (int j = 0; j < 8; ++j)
                accT[i][j] += accC[i][j];
    }

    __syncthreads();   // all As/Bs reads done before Sc overwrite (aliased)

    // biased sigmoid scores -> Sc
    #pragma unroll
    for (int i = 0; i < 8; ++i)
        #pragma unroll
        for (int j = 0; j < 8; ++j) {
            const float s = 1.0f / (1.0f + expf(-accT[i][j]));
            Sc[(r0 + i) * SC_STRIDE + (c0 + j)] = s + biasS[c0 + j];
        }
    __syncthreads();

    // ---- routing (fp32) + margin check: one thread per token ----
    if (tid < BM) {
        float* row = &Sc[tid * SC_STRIDE];

        float gs[NGROUP];
        for (int g = 0; g < NGROUP; ++g) {
            const int base = g * GSIZE;
            float m1 = -3e38f, m2 = -3e38f;
            for (int j = 0; j < GSIZE; ++j) {
                const float v = row[base + j];
                if (v > m1) { m2 = m1; m1 = v; }
                else if (v > m2) { m2 = v; }
            }
            gs[g] = m1 + m2;
        }

        unsigned gsel = 0;
        float minSel = 3e38f, maxUn = -3e38f;
        #pragma unroll
        for (int g = 0; g < NGROUP; ++g) {
            int rank = 0;
            #pragma unroll
            for (int h = 0; h < NGROUP; ++h)
                rank += (gs[h] > gs[g]) || (gs[h] == gs[g] && h < g);
            if (rank < TOPG) { gsel |= 1u << g; minSel = fminf(minSel, gs[g]); }
            else             { maxUn = fmaxf(maxUn, gs[g]); }
        }
        float minMargin = minSel - maxUn;

        // top-9 scan (8 selections + boundary), margins between consecutive
        float wk[TOPK];
        int   ik[TOPK];
        float wsum = 0.0f;
        float prev = 3e38f;
        #pragma unroll
        for (int k = 0; k < TOPK + 1; ++k) {
            float bv = -3e38f;
            int   bi = 0;
            for (int g = 0; g < NGROUP; ++g) {
                if (!((gsel >> g) & 1u)) continue;
                const int base = g * GSIZE;
                for (int j = 0; j < GSIZE; ++j) {
                    const int e = base + j;
                    const float v = row[e];
                    if (v > bv) { bv = v; bi = e; }
                }
            }
            if (k > 0) minMargin = fminf(minMargin, prev - bv);
            prev = bv;
            if (k < TOPK) {
                const float w = bv - biasS[bi];
                wk[k] = w; ik[k] = bi; wsum += w;
                row[bi] = -3e38f;
            }
        }

        const float norm = (float)SCALE / wsum;
        const size_t t = (size_t)(t0 + tid);
        float* oi = out + t * TOPK;
        float* ow = out + (size_t)T_TOKENS * TOPK + t * TOPK;
        #pragma unroll
        for (int k = 0; k < TOPK; ++k) {
            oi[k] = (float)ik[k];
            ow[k] = wk[k] * norm;
        }

        if (minMargin < TAU) {
            const int r = atomicAdd(ws, 1);
            ws[RLIST_OFF + r] = t0 + tid;
        }
    }
}

// -------------------------------------------------------------- rescue ----
#define RB 4   // tokens per block-iteration
__global__ void router_rescue(
    const float* __restrict__ H,
    const float* __restrict__ Wt,
    const float* __restrict__ bias,
    float* __restrict__ out,
    const int* __restrict__ ws)
{
    __shared__ double Hs[RB][DIM];     // 64 KiB
    __shared__ double Ssc[RB][NEXP];   //  8 KiB

    const int tid = threadIdx.x;
    const int nR  = ws[0];

    for (int base = blockIdx.x * RB; base < nR; base += gridDim.x * RB) {
        const int nt = min(RB, nR - base);
        __syncthreads();   // previous iteration's Ssc reads done

        // stage H rows as f64
        for (int j = 0; j < nt; ++j) {
            const int t = ws[RLIST_OFF + base + j];
            const float* hp = H + (size_t)t * DIM + tid * 8;
            const float4 v0 = *(const float4*)hp;
            const float4 v1 = *(const float4*)(hp + 4);
            double* d = &Hs[j][tid * 8];
            d[0] = (double)v0.x; d[1] = (double)v0.y; d[2] = (double)v0.z; d[3] = (double)v0.w;
            d[4] = (double)v1.x; d[5] = (double)v1.y; d[6] = (double)v1.z; d[7] = (double)v1.w;
        }
        __syncthreads();

        // fp64 dot: thread = expert, sequential-k chain
        double acc[RB] = {0.0, 0.0, 0.0, 0.0};
        const float* wr = Wt + (size_t)tid * DIM;
        for (int k = 0; k < DIM; k += 4) {
            const float4 wv = *(const float4*)(wr + k);
            const double w0 = (double)wv.x, w1 = (double)wv.y;
            const double w2 = (double)wv.z, w3 = (double)wv.w;
            #pragma unroll
            for (int j = 0; j < RB; ++j) {
                acc[j] = fma(Hs[j][k + 0], w0, acc[j]);
                acc[j] = fma(Hs[j][k + 1], w1, acc[j]);
                acc[j] = fma(Hs[j][k + 2], w2, acc[j]);
                acc[j] = fma(Hs[j][k + 3], w3, acc[j]);
            }
        }
        const double bd = (double)bias[tid];
        #pragma unroll
        for (int j = 0; j < RB; ++j)
            Ssc[j][tid] = 1.0 / (1.0 + exp(-acc[j])) + bd;
        __syncthreads();

        // exact fp64 routing (round-2-proven), one thread per token
        if (tid < nt) {
            double* row = Ssc[tid];

            double gs[NGROUP];
            for (int g = 0; g < NGROUP; ++g) {
                const int b0 = g * GSIZE;
                double m1 = -1e300, m2 = -1e300;
                for (int j = 0; j < GSIZE; ++j) {
                    const double v = row[b0 + j];
                    if (v > m1) { m2 = m1; m1 = v; }
                    else if (v > m2) { m2 = v; }
                }
                gs[g] = m1 + m2;
            }

            unsigned gsel = 0;
            for (int g = 0; g < NGROUP; ++g) {
                int rank = 0;
                for (int h = 0; h < NGROUP; ++h)
                    rank += (gs[h] > gs[g]) || (gs[h] == gs[g] && h < g);
                if (rank < TOPG) gsel |= 1u << g;
            }

            double wk[TOPK];
            int    ik[TOPK];
            double wsum = 0.0;
            for (int k = 0; k < TOPK; ++k) {
                double bv = -1e300;
                int    bi = 0;
                for (int g = 0; g < NGROUP; ++g) {
                    if (!((gsel >> g) & 1u)) continue;
                    const int b0 = g * GSIZE;
                    for (int j = 0; j < GSIZE; ++j) {
                        const int e = b0 + j;
                        if (row[e] > bv) { bv = row[e]; bi = e; }
                    }
                }
                const double w = bv - (double)bias[bi];
                wk[k] = w; ik[k] = bi; wsum += w;
                row[bi] = -1e300;
            }

            const double norm = SCALE / wsum;
            const int t = ws[RLIST_OFF + base + tid];
            float* oi = out + (size_t)t * TOPK;
            float* ow = out + (size_t)T_TOKENS * TOPK + (size_t)t * TOPK;
            for (int k = 0; k < TOPK; ++k) {
                oi[k] = (float)ik[k];
                ow[k] = (float)(wk[k] * norm);
            }
        }
    }
}

extern "C" void kernel_launch(void* const* d_in, const int* in_sizes, int n_in,
                              void* d_out, int out_size, void* d_ws, size_t ws_size,
                              hipStream_t stream) {
    const float* H    = (const float*)d_in[0];
    const float* Wt   = (const float*)d_in[1];
    const float* bias = (const float*)d_in[2];
    float* out = (float*)d_out;
    int*   ws  = (int*)d_ws;

    zero_counter<<<1, 64, 0, stream>>>(ws);
    router_main<<<T_TOKENS / BM, 256, 0, stream>>>(H, Wt, bias, out, ws);
    router_rescue<<<256, 256, 0, stream>>>(H, Wt, bias, out, ws);
}

// Round 5
// 293.447 us; speedup vs baseline: 6.3210x; 2.9946x over previous
//
#include <hip/hip_runtime.h>
#include <math.h>

// Problem constants
#define T_TOKENS 32768
#define DIM      2048
#define NEXP     256
#define NGROUP   8
#define GSIZE    32
#define TOPG     4
#define TOPK     8
#define SCALE    2.5
#define TAU      2e-5f     // rescue margin; 3-term bf16-split err sigma ~4e-7

// Main-pass tiling
#define BM 64
#define NSTEP 64           // K-steps of 32
#define SC_STRIDE 257

#define RLIST_OFF 16                 // ints; ws[0] = counter
#define WPACK_OFF_BYTES (1 << 18)    // 256 KiB into d_ws

typedef __attribute__((ext_vector_type(8))) short bf16x8;
typedef __attribute__((ext_vector_type(8))) unsigned short u16x8;
typedef __attribute__((ext_vector_type(4))) float f32x4;

__device__ __forceinline__ unsigned short f2bf_rne(float f) {
    unsigned u = __float_as_uint(f);
    u += 0x7fffu + ((u >> 16) & 1u);
    return (unsigned short)(u >> 16);
}
__device__ __forceinline__ float bf2f(unsigned short h) {
    return __uint_as_float(((unsigned)h) << 16);
}

// ---------------------------------------------------------------- init ----
__global__ void zero_counter(int* ws) {
    if (threadIdx.x == 0) ws[0] = 0;
}

// ------------------------------------------------------------- pack W ----
// Wpack slot (s, n, h, lane) holds 8 bf16: W[e=16n+(lane&15)][k=32s+(lane>>4)*8+i]
// elem offset = (((s*16+n)*2 + h)*64 + lane)*8
__global__ void pack_w_kernel(const float* __restrict__ Wt,
                              unsigned short* __restrict__ wp) {
    const int slot = blockIdx.x * 256 + threadIdx.x;   // 0..65535
    const int lane = slot & 63;
    const int n    = (slot >> 6) & 15;
    const int s    = slot >> 10;
    const int e    = n * 16 + (lane & 15);
    const int k0   = s * 32 + (lane >> 4) * 8;
    const float* src = Wt + (size_t)e * DIM + k0;
    const float4 v0 = *(const float4*)src;
    const float4 v1 = *(const float4*)(src + 4);
    const float a[8] = {v0.x, v0.y, v0.z, v0.w, v1.x, v1.y, v1.z, v1.w};
    union { unsigned short u[8]; u16x8 v; } uh, ul;
    #pragma unroll
    for (int i = 0; i < 8; ++i) {
        const unsigned short hb = f2bf_rne(a[i]);
        uh.u[i] = hb;
        ul.u[i] = f2bf_rne(a[i] - bf2f(hb));
    }
    const size_t base = ((size_t)(s * 16 + n) * 2) * 64 + lane;
    *(u16x8*)(wp + base * 8)        = uh.v;   // hi
    *(u16x8*)(wp + (base + 64) * 8) = ul.v;   // lo
}

// ---------------------------------------------------------------- main ----
__global__ __launch_bounds__(256, 2) void router_main(
    const float* __restrict__ H,
    const float* __restrict__ bias,
    const unsigned short* __restrict__ wp,
    float* __restrict__ out,
    int* __restrict__ ws)
{
    __shared__ __align__(16) unsigned short Ahl[2][4][64][8];  // 8 KiB [h][m][lane][i]
    __shared__ float Sc[BM * SC_STRIDE];                       // 65.8 KiB
    __shared__ float biasS[NEXP];

    const int tid  = threadIdx.x;
    const int lane = tid & 63;
    const int w    = tid >> 6;
    const int t0   = blockIdx.x * BM;

    biasS[tid] = bias[tid];

    f32x4 acc[4][4];   // [m][j]
    #pragma unroll
    for (int m = 0; m < 4; ++m)
        #pragma unroll
        for (int j = 0; j < 4; ++j)
            acc[m][j] = (f32x4){0.f, 0.f, 0.f, 0.f};

    // A staging mapping: thread -> (row, k-quad)
    const int arow = tid >> 2;          // 0..63
    const int kq   = tid & 3;           // 0..3
    const float* Aptr = H + (size_t)(t0 + arow) * DIM + kq * 8;
    const int lw = (kq << 4) | (arow & 15);
    unsigned short* awr_h = &Ahl[0][arow >> 4][lw][0];
    unsigned short* awr_l = &Ahl[1][arow >> 4][lw][0];

    float4 h0 = *(const float4*)(Aptr);
    float4 h1 = *(const float4*)(Aptr + 4);

    auto loadB = [&](int s, bf16x8 (&Bh)[4], bf16x8 (&Bl)[4]) {
        #pragma unroll
        for (int j = 0; j < 4; ++j) {
            const size_t slot = ((size_t)(s * 16 + 4 * w + j) * 2) * 64 + lane;
            Bh[j] = *(const bf16x8*)(wp + slot * 8);
            Bl[j] = *(const bf16x8*)(wp + (slot + 64) * 8);
        }
    };
    auto stageA = [&]() {
        const float a[8] = {h0.x, h0.y, h0.z, h0.w, h1.x, h1.y, h1.z, h1.w};
        union { unsigned short u[8]; u16x8 v; } uh, ul;
        #pragma unroll
        for (int i = 0; i < 8; ++i) {
            const unsigned short hb = f2bf_rne(a[i]);
            uh.u[i] = hb;
            ul.u[i] = f2bf_rne(a[i] - bf2f(hb));
        }
        *(u16x8*)awr_h = uh.v;
        *(u16x8*)awr_l = ul.v;
    };
    auto compute = [&](bf16x8 (&Bh)[4], bf16x8 (&Bl)[4]) {
        bf16x8 Ah[4], Al[4];
        #pragma unroll
        for (int m = 0; m < 4; ++m) {
            Ah[m] = *(const bf16x8*)&Ahl[0][m][lane][0];
            Al[m] = *(const bf16x8*)&Ahl[1][m][lane][0];
        }
        #pragma unroll
        for (int m = 0; m < 4; ++m)
            #pragma unroll
            for (int j = 0; j < 4; ++j) {
                acc[m][j] = __builtin_amdgcn_mfma_f32_16x16x32_bf16(Al[m], Bh[j], acc[m][j], 0, 0, 0);
                acc[m][j] = __builtin_amdgcn_mfma_f32_16x16x32_bf16(Ah[m], Bl[j], acc[m][j], 0, 0, 0);
                acc[m][j] = __builtin_amdgcn_mfma_f32_16x16x32_bf16(Ah[m], Bh[j], acc[m][j], 0, 0, 0);
            }
    };

    bf16x8 B0h[4], B0l[4], B1h[4], B1l[4];
    loadB(0, B0h, B0l);

    for (int s = 0; s < NSTEP; s += 2) {
        __syncthreads();
        stageA();                       // step s
        __syncthreads();
        {   // prefetch H(s+1), B(s+1); hidden under compute
            const float* p = Aptr + (size_t)(s + 1) * 32;
            h0 = *(const float4*)p;
            h1 = *(const float4*)(p + 4);
        }
        loadB(s + 1, B1h, B1l);
        compute(B0h, B0l);

        __syncthreads();
        stageA();                       // step s+1
        __syncthreads();
        if (s + 2 < NSTEP) {
            const float* p = Aptr + (size_t)(s + 2) * 32;
            h0 = *(const float4*)p;
            h1 = *(const float4*)(p + 4);
            loadB(s + 2, B0h, B0l);
        }
        compute(B1h, B1l);
    }

    // ---- epilogue: biased sigmoid -> Sc ----
    const int rbase = (lane >> 4) * 4;
    const int cc    = lane & 15;
    #pragma unroll
    for (int m = 0; m < 4; ++m)
        #pragma unroll
        for (int j = 0; j < 4; ++j)
            #pragma unroll
            for (int r = 0; r < 4; ++r) {
                const int token  = 16 * m + rbase + r;
                const int expert = 64 * w + 16 * j + cc;
                const float sg = 1.0f / (1.0f + expf(-acc[m][j][r]));
                Sc[token * SC_STRIDE + expert] = sg + biasS[expert];
            }
    __syncthreads();

    // ---- routing (fp32) + margin check (round-4 proven) ----
    if (tid < BM) {
        float* row = &Sc[tid * SC_STRIDE];

        float gs[NGROUP];
        for (int g = 0; g < NGROUP; ++g) {
            const int base = g * GSIZE;
            float m1 = -3e38f, m2 = -3e38f;
            for (int j = 0; j < GSIZE; ++j) {
                const float v = row[base + j];
                if (v > m1) { m2 = m1; m1 = v; }
                else if (v > m2) { m2 = v; }
            }
            gs[g] = m1 + m2;
        }

        unsigned gsel = 0;
        float minSel = 3e38f, maxUn = -3e38f;
        #pragma unroll
        for (int g = 0; g < NGROUP; ++g) {
            int rank = 0;
            #pragma unroll
            for (int h = 0; h < NGROUP; ++h)
                rank += (gs[h] > gs[g]) || (gs[h] == gs[g] && h < g);
            if (rank < TOPG) { gsel |= 1u << g; minSel = fminf(minSel, gs[g]); }
            else             { maxUn = fmaxf(maxUn, gs[g]); }
        }
        float minMargin = minSel - maxUn;

        float wk[TOPK];
        int   ik[TOPK];
        float wsum = 0.0f;
        float prev = 3e38f;
        #pragma unroll
        for (int k = 0; k < TOPK + 1; ++k) {
            float bv = -3e38f;
            int   bi = 0;
            for (int g = 0; g < NGROUP; ++g) {
                if (!((gsel >> g) & 1u)) continue;
                const int base = g * GSIZE;
                for (int j = 0; j < GSIZE; ++j) {
                    const int e = base + j;
                    const float v = row[e];
                    if (v > bv) { bv = v; bi = e; }
                }
            }
            if (k > 0) minMargin = fminf(minMargin, prev - bv);
            prev = bv;
            if (k < TOPK) {
                const float wv = bv - biasS[bi];
                wk[k] = wv; ik[k] = bi; wsum += wv;
                row[bi] = -3e38f;
            }
        }

        const float norm = (float)SCALE / wsum;
        const size_t t = (size_t)(t0 + tid);
        float* oi = out + t * TOPK;
        float* ow = out + (size_t)T_TOKENS * TOPK + t * TOPK;
        #pragma unroll
        for (int k = 0; k < TOPK; ++k) {
            oi[k] = (float)ik[k];
            ow[k] = wk[k] * norm;
        }

        if (minMargin < TAU) {
            const int r = atomicAdd(ws, 1);
            ws[RLIST_OFF + r] = t0 + tid;
        }
    }
}

// -------------------------------------------------------------- rescue ----
// 2 tokens per block-iteration; threads = 64 experts x 4 k-chunks; exact fp64.
__global__ __launch_bounds__(256) void router_rescue(
    const float* __restrict__ H,
    const float* __restrict__ Wt,
    const float* __restrict__ bias,
    float* __restrict__ out,
    const int* __restrict__ ws)
{
    __shared__ float  Hs[2][DIM];          // 16 KiB
    __shared__ double Part[4][2][NEXP];    // 16 KiB
    __shared__ double Sd[2][NEXP];         //  4 KiB

    const int tid = threadIdx.x;
    const int nR  = ws[0];
    const int e0  = tid & 63;
    const int kc  = tid >> 6;              // 0..3

    for (int base = blockIdx.x * 2; base < nR; base += gridDim.x * 2) {
        const int nt = min(2, nR - base);
        __syncthreads();

        for (int j = 0; j < nt; ++j) {
            const int t = ws[RLIST_OFF + base + j];
            const float* hp = H + (size_t)t * DIM + tid * 8;
            const float4 a = *(const float4*)hp;
            const float4 b = *(const float4*)(hp + 4);
            float* d = &Hs[j][tid * 8];
            d[0] = a.x; d[1] = a.y; d[2] = a.z; d[3] = a.w;
            d[4] = b.x; d[5] = b.y; d[6] = b.z; d[7] = b.w;
        }
        __syncthreads();

        #pragma unroll
        for (int q = 0; q < 4; ++q) {
            const int e = e0 + 64 * q;
            const float* wr  = Wt + (size_t)e * DIM + kc * 512;
            const float* h0p = &Hs[0][kc * 512];
            const float* h1p = &Hs[1][kc * 512];
            double a0 = 0.0, a1 = 0.0;
            for (int k = 0; k < 512; k += 4) {
                const float4 wv = *(const float4*)(wr + k);
                const double w0 = (double)wv.x, w1 = (double)wv.y;
                const double w2 = (double)wv.z, w3 = (double)wv.w;
                a0 = fma((double)h0p[k + 0], w0, a0);
                a0 = fma((double)h0p[k + 1], w1, a0);
                a0 = fma((double)h0p[k + 2], w2, a0);
                a0 = fma((double)h0p[k + 3], w3, a0);
                a1 = fma((double)h1p[k + 0], w0, a1);
                a1 = fma((double)h1p[k + 1], w1, a1);
                a1 = fma((double)h1p[k + 2], w2, a1);
                a1 = fma((double)h1p[k + 3], w3, a1);
            }
            Part[kc][0][e] = a0;
            Part[kc][1][e] = a1;
        }
        __syncthreads();

        {   // reduce chunks (fixed order) + fp64 sigmoid + bias
            const int e = tid;
            #pragma unroll
            for (int j = 0; j < 2; ++j) {
                const double sum = ((Part[0][j][e] + Part[1][j][e]) + Part[2][j][e]) + Part[3][j][e];
                Sd[j][e] = 1.0 / (1.0 + exp(-sum)) + (double)bias[e];
            }
        }
        __syncthreads();

        if (tid < nt) {
            double* row = Sd[tid];

            double gs[NGROUP];
            for (int g = 0; g < NGROUP; ++g) {
                const int b0 = g * GSIZE;
                double m1 = -1e300, m2 = -1e300;
                for (int j = 0; j < GSIZE; ++j) {
                    const double v = row[b0 + j];
                    if (v > m1) { m2 = m1; m1 = v; }
                    else if (v > m2) { m2 = v; }
                }
                gs[g] = m1 + m2;
            }

            unsigned gsel = 0;
            for (int g = 0; g < NGROUP; ++g) {
                int rank = 0;
                for (int h = 0; h < NGROUP; ++h)
                    rank += (gs[h] > gs[g]) || (gs[h] == gs[g] && h < g);
                if (rank < TOPG) gsel |= 1u << g;
            }

            double wk[TOPK];
            int    ik[TOPK];
            double wsum = 0.0;
            for (int k = 0; k < TOPK; ++k) {
                double bv = -1e300;
                int    bi = 0;
                for (int g = 0; g < NGROUP; ++g) {
                    if (!((gsel >> g) & 1u)) continue;
                    const int b0 = g * GSIZE;
                    for (int j = 0; j < GSIZE; ++j) {
                        const int e = b0 + j;
                        if (row[e] > bv) { bv = row[e]; bi = e; }
                    }
                }
                const double wv = bv - (double)bias[bi];
                wk[k] = wv; ik[k] = bi; wsum += wv;
                row[bi] = -1e300;
            }

            const double norm = SCALE / wsum;
            const int t = ws[RLIST_OFF + base + tid];
            float* oi = out + (size_t)t * TOPK;
            float* ow = out + (size_t)T_TOKENS * TOPK + (size_t)t * TOPK;
            for (int k = 0; k < TOPK; ++k) {
                oi[k] = (float)ik[k];
                ow[k] = (float)(wk[k] * norm);
            }
        }
    }
}

extern "C" void kernel_launch(void* const* d_in, const int* in_sizes, int n_in,
                              void* d_out, int out_size, void* d_ws, size_t ws_size,
                              hipStream_t stream) {
    const float* H    = (const float*)d_in[0];
    const float* Wt   = (const float*)d_in[1];
    const float* bias = (const float*)d_in[2];
    float* out = (float*)d_out;
    int*   ws  = (int*)d_ws;
    unsigned short* wp = (unsigned short*)((char*)d_ws + WPACK_OFF_BYTES);

    zero_counter<<<1, 64, 0, stream>>>(ws);
    pack_w_kernel<<<256, 256, 0, stream>>>(Wt, wp);
    router_main<<<T_TOKENS / BM, 256, 0, stream>>>(H, bias, wp, out, ws);
    router_rescue<<<512, 256, 0, stream>>>(H, Wt, bias, out, ws);
}

// Round 6
// 281.359 us; speedup vs baseline: 6.5926x; 1.0430x over previous
//
#include <hip/hip_runtime.h>
#include <math.h>

// Problem constants
#define T_TOKENS 32768
#define DIM      2048
#define NEXP     256
#define NGROUP   8
#define GSIZE    32
#define TOPG     4
#define TOPK     8
#define SCALE    2.5
#define TAU      2e-5f     // rescue margin; 3-term bf16-split err sigma ~4e-7

// Main-pass tiling
#define BM  64
#define NIT 32             // iterations of 64-k (2 sub-steps of 32)
#define SC_STRIDE 257

#define RLIST_OFF 16                 // ints; ws[0] = counter
#define WPACK_OFF_BYTES (1 << 18)    // 256 KiB into d_ws

typedef __attribute__((ext_vector_type(8))) short bf16x8;
typedef __attribute__((ext_vector_type(8))) unsigned short u16x8;
typedef __attribute__((ext_vector_type(4))) float f32x4;

__device__ __forceinline__ unsigned short f2bf_rne(float f) {
    unsigned u = __float_as_uint(f);
    u += 0x7fffu + ((u >> 16) & 1u);
    return (unsigned short)(u >> 16);
}
__device__ __forceinline__ float bf2f(unsigned short h) {
    return __uint_as_float(((unsigned)h) << 16);
}

// ---------------------------------------------------------------- init ----
__global__ void zero_counter(int* ws) {
    if (threadIdx.x == 0) ws[0] = 0;
}

// ------------------------------------------------------------- pack W ----
// Wpack slot (s, n, h, lane) holds 8 bf16: W[e=16n+(lane&15)][k=32s+(lane>>4)*8+i]
__global__ void pack_w_kernel(const float* __restrict__ Wt,
                              unsigned short* __restrict__ wp) {
    const int slot = blockIdx.x * 256 + threadIdx.x;   // 0..65535
    const int lane = slot & 63;
    const int n    = (slot >> 6) & 15;
    const int s    = slot >> 10;
    const int e    = n * 16 + (lane & 15);
    const int k0   = s * 32 + (lane >> 4) * 8;
    const float* src = Wt + (size_t)e * DIM + k0;
    const float4 v0 = *(const float4*)src;
    const float4 v1 = *(const float4*)(src + 4);
    const float a[8] = {v0.x, v0.y, v0.z, v0.w, v1.x, v1.y, v1.z, v1.w};
    union { unsigned short u[8]; u16x8 v; } uh, ul;
    #pragma unroll
    for (int i = 0; i < 8; ++i) {
        const unsigned short hb = f2bf_rne(a[i]);
        uh.u[i] = hb;
        ul.u[i] = f2bf_rne(a[i] - bf2f(hb));
    }
    const size_t base = ((size_t)(s * 16 + n) * 2) * 64 + lane;
    *(u16x8*)(wp + base * 8)        = uh.v;   // hi
    *(u16x8*)(wp + (base + 64) * 8) = ul.v;   // lo
}

// ---------------------------------------------------------------- main ----
__global__ __launch_bounds__(256, 2) void router_main(
    const float* __restrict__ H,
    const float* __restrict__ bias,
    const unsigned short* __restrict__ wp,
    float* __restrict__ out,
    int* __restrict__ ws)
{
    // union: Ahl dbuf (32 KiB) / Sc (65792 B)
    __shared__ __align__(16) char smraw[BM * SC_STRIDE * 4];
    __shared__ float biasS[NEXP];

    typedef unsigned short AhlBuf[2][2][4][64][8];   // [sub][h][m][lane][i]
    AhlBuf* Ahl = reinterpret_cast<AhlBuf*>(smraw);  // Ahl[buf]
    float*  Sc  = reinterpret_cast<float*>(smraw);

    const int tid  = threadIdx.x;
    const int lane = tid & 63;
    const int w    = tid >> 6;
    const int t0   = blockIdx.x * BM;

    biasS[tid] = bias[tid];

    f32x4 acc[4][4];
    #pragma unroll
    for (int m = 0; m < 4; ++m)
        #pragma unroll
        for (int j = 0; j < 4; ++j)
            acc[m][j] = (f32x4){0.f, 0.f, 0.f, 0.f};

    // A staging mapping
    const int arow = tid >> 2;          // 0..63
    const int kq   = tid & 3;           // 0..3
    const int am   = arow >> 4;
    const int lw   = (kq << 4) | (arow & 15);
    const float* Aptr = H + (size_t)(t0 + arow) * DIM + kq * 8;

    auto stageSub = [&](int b, int sub, const float4& x0, const float4& x1) {
        const float a[8] = {x0.x, x0.y, x0.z, x0.w, x1.x, x1.y, x1.z, x1.w};
        union { unsigned short u[8]; u16x8 v; } uh, ul;
        #pragma unroll
        for (int i = 0; i < 8; ++i) {
            const unsigned short hb = f2bf_rne(a[i]);
            uh.u[i] = hb;
            ul.u[i] = f2bf_rne(a[i] - bf2f(hb));
        }
        *(u16x8*)&Ahl[b][sub][0][am][lw][0] = uh.v;
        *(u16x8*)&Ahl[b][sub][1][am][lw][0] = ul.v;
    };
    auto loadB = [&](int sub, bf16x8 (&Bh)[4], bf16x8 (&Bl)[4]) {
        #pragma unroll
        for (int j = 0; j < 4; ++j) {
            const size_t slot = ((size_t)(sub * 16 + 4 * w + j) * 2) * 64 + lane;
            Bh[j] = *(const bf16x8*)(wp + slot * 8);
            Bl[j] = *(const bf16x8*)(wp + (slot + 64) * 8);
        }
    };
    auto computeSub = [&](int b, int sub, bf16x8 (&Bh)[4], bf16x8 (&Bl)[4]) {
        bf16x8 Ah[4], Al[4];
        #pragma unroll
        for (int m = 0; m < 4; ++m) {
            Ah[m] = *(const bf16x8*)&Ahl[b][sub][0][m][lane][0];
            Al[m] = *(const bf16x8*)&Ahl[b][sub][1][m][lane][0];
        }
        #pragma unroll
        for (int m = 0; m < 4; ++m)
            #pragma unroll
            for (int j = 0; j < 4; ++j) {
                acc[m][j] = __builtin_amdgcn_mfma_f32_16x16x32_bf16(Al[m], Bh[j], acc[m][j], 0, 0, 0);
                acc[m][j] = __builtin_amdgcn_mfma_f32_16x16x32_bf16(Ah[m], Bl[j], acc[m][j], 0, 0, 0);
                acc[m][j] = __builtin_amdgcn_mfma_f32_16x16x32_bf16(Ah[m], Bh[j], acc[m][j], 0, 0, 0);
            }
    };
    auto loadH4 = [&](int it, float4& x0, float4& x1, float4& y0, float4& y1) {
        const float* p = Aptr + (size_t)it * 64;
        x0 = *(const float4*)p;        x1 = *(const float4*)(p + 4);
        y0 = *(const float4*)(p + 32); y1 = *(const float4*)(p + 36);
    };

    bf16x8 Ba_h[4], Ba_l[4], Bb_h[4], Bb_l[4];
    float4 hS0, hS1, hS2, hS3, hL0, hL1, hL2, hL3;

    // prologue: stage iter 0 into buf0, prefetch h(1), B(sub 0)
    {
        float4 c0, c1, c2, c3;
        loadH4(0, c0, c1, c2, c3);
        stageSub(0, 0, c0, c1);
        stageSub(0, 1, c2, c3);
    }
    loadH4(1, hS0, hS1, hS2, hS3);
    loadB(0, Ba_h, Ba_l);
    __syncthreads();

    for (int s = 0; s < NIT; s += 2) {
        // ---- iter s: compute buf0 (subs 2s,2s+1); stage buf1 = A(s+1) ----
        loadH4(min(s + 2, NIT - 1), hL0, hL1, hL2, hL3);     // h for A(s+2)
        stageSub(1, 0, hS0, hS1);
        stageSub(1, 1, hS2, hS3);
        loadB(2 * s + 1, Bb_h, Bb_l);
        computeSub(0, 0, Ba_h, Ba_l);
        loadB(min(2 * s + 2, 2 * NIT - 1), Ba_h, Ba_l);
        computeSub(0, 1, Bb_h, Bb_l);
        __syncthreads();

        // ---- iter s+1: compute buf1; stage buf0 = A(s+2) ----
        loadH4(min(s + 3, NIT - 1), hS0, hS1, hS2, hS3);     // h for A(s+3)
        if (s + 2 < NIT) { stageSub(0, 0, hL0, hL1); stageSub(0, 1, hL2, hL3); }
        loadB(min(2 * s + 3, 2 * NIT - 1), Bb_h, Bb_l);
        computeSub(1, 0, Ba_h, Ba_l);
        loadB(min(2 * s + 4, 2 * NIT - 1), Ba_h, Ba_l);
        computeSub(1, 1, Bb_h, Bb_l);
        __syncthreads();
    }

    // ---- epilogue: biased sigmoid -> Sc ----
    const int rbase = (lane >> 4) * 4;
    const int cc    = lane & 15;
    #pragma unroll
    for (int m = 0; m < 4; ++m)
        #pragma unroll
        for (int j = 0; j < 4; ++j)
            #pragma unroll
            for (int r = 0; r < 4; ++r) {
                const int token  = 16 * m + rbase + r;
                const int expert = 64 * w + 16 * j + cc;
                const float sg = 1.0f / (1.0f + expf(-acc[m][j][r]));
                Sc[token * SC_STRIDE + expert] = sg + biasS[expert];
            }
    __syncthreads();

    // ---- routing (fp32) + margin check (round-4/5 proven) ----
    if (tid < BM) {
        float* row = &Sc[tid * SC_STRIDE];

        float gs[NGROUP];
        for (int g = 0; g < NGROUP; ++g) {
            const int base = g * GSIZE;
            float m1 = -3e38f, m2 = -3e38f;
            for (int j = 0; j < GSIZE; ++j) {
                const float v = row[base + j];
                if (v > m1) { m2 = m1; m1 = v; }
                else if (v > m2) { m2 = v; }
            }
            gs[g] = m1 + m2;
        }

        unsigned gsel = 0;
        float minSel = 3e38f, maxUn = -3e38f;
        #pragma unroll
        for (int g = 0; g < NGROUP; ++g) {
            int rank = 0;
            #pragma unroll
            for (int h = 0; h < NGROUP; ++h)
                rank += (gs[h] > gs[g]) || (gs[h] == gs[g] && h < g);
            if (rank < TOPG) { gsel |= 1u << g; minSel = fminf(minSel, gs[g]); }
            else             { maxUn = fmaxf(maxUn, gs[g]); }
        }
        float minMargin = minSel - maxUn;

        float wk[TOPK];
        int   ik[TOPK];
        float wsum = 0.0f;
        float prev = 3e38f;
        #pragma unroll
        for (int k = 0; k < TOPK + 1; ++k) {
            float bv = -3e38f;
            int   bi = 0;
            for (int g = 0; g < NGROUP; ++g) {
                if (!((gsel >> g) & 1u)) continue;
                const int base = g * GSIZE;
                for (int j = 0; j < GSIZE; ++j) {
                    const int e = base + j;
                    const float v = row[e];
                    if (v > bv) { bv = v; bi = e; }
                }
            }
            if (k > 0) minMargin = fminf(minMargin, prev - bv);
            prev = bv;
            if (k < TOPK) {
                const float wv = bv - biasS[bi];
                wk[k] = wv; ik[k] = bi; wsum += wv;
                row[bi] = -3e38f;
            }
        }

        const float norm = (float)SCALE / wsum;
        const size_t t = (size_t)(t0 + tid);
        float* oi = out + t * TOPK;
        float* ow = out + (size_t)T_TOKENS * TOPK + t * TOPK;
        #pragma unroll
        for (int k = 0; k < TOPK; ++k) {
            oi[k] = (float)ik[k];
            ow[k] = wk[k] * norm;
        }

        if (minMargin < TAU) {
            const int r = atomicAdd(ws, 1);
            ws[RLIST_OFF + r] = t0 + tid;
        }
    }
}

// -------------------------------------------------------------- rescue ----
// 2 tokens per block-iteration; threads = 64 experts x 4 k-chunks; exact fp64.
__global__ __launch_bounds__(256) void router_rescue(
    const float* __restrict__ H,
    const float* __restrict__ Wt,
    const float* __restrict__ bias,
    float* __restrict__ out,
    const int* __restrict__ ws)
{
    __shared__ float  Hs[2][DIM];          // 16 KiB
    __shared__ double Part[4][2][NEXP];    // 16 KiB
    __shared__ double Sd[2][NEXP];         //  4 KiB

    const int tid = threadIdx.x;
    const int nR  = ws[0];
    const int e0  = tid & 63;
    const int kc  = tid >> 6;              // 0..3

    for (int base = blockIdx.x * 2; base < nR; base += gridDim.x * 2) {
        const int nt = min(2, nR - base);
        __syncthreads();

        for (int j = 0; j < nt; ++j) {
            const int t = ws[RLIST_OFF + base + j];
            const float* hp = H + (size_t)t * DIM + tid * 8;
            const float4 a = *(const float4*)hp;
            const float4 b = *(const float4*)(hp + 4);
            float* d = &Hs[j][tid * 8];
            d[0] = a.x; d[1] = a.y; d[2] = a.z; d[3] = a.w;
            d[4] = b.x; d[5] = b.y; d[6] = b.z; d[7] = b.w;
        }
        __syncthreads();

        #pragma unroll
        for (int q = 0; q < 4; ++q) {
            const int e = e0 + 64 * q;
            const float* wr  = Wt + (size_t)e * DIM + kc * 512;
            const float* h0p = &Hs[0][kc * 512];
            const float* h1p = &Hs[1][kc * 512];
            double a00 = 0.0, a01 = 0.0, a10 = 0.0, a11 = 0.0;   // 4 indep chains
            for (int k = 0; k < 512; k += 8) {
                const float4 w0 = *(const float4*)(wr + k);
                const float4 w1 = *(const float4*)(wr + k + 4);
                a00 = fma((double)h0p[k + 0], (double)w0.x, a00);
                a00 = fma((double)h0p[k + 1], (double)w0.y, a00);
                a00 = fma((double)h0p[k + 2], (double)w0.z, a00);
                a00 = fma((double)h0p[k + 3], (double)w0.w, a00);
                a01 = fma((double)h0p[k + 4], (double)w1.x, a01);
                a01 = fma((double)h0p[k + 5], (double)w1.y, a01);
                a01 = fma((double)h0p[k + 6], (double)w1.z, a01);
                a01 = fma((double)h0p[k + 7], (double)w1.w, a01);
                a10 = fma((double)h1p[k + 0], (double)w0.x, a10);
                a10 = fma((double)h1p[k + 1], (double)w0.y, a10);
                a10 = fma((double)h1p[k + 2], (double)w0.z, a10);
                a10 = fma((double)h1p[k + 3], (double)w0.w, a10);
                a11 = fma((double)h1p[k + 4], (double)w1.x, a11);
                a11 = fma((double)h1p[k + 5], (double)w1.y, a11);
                a11 = fma((double)h1p[k + 6], (double)w1.z, a11);
                a11 = fma((double)h1p[k + 7], (double)w1.w, a11);
            }
            Part[kc][0][e] = a00 + a01;
            Part[kc][1][e] = a10 + a11;
        }
        __syncthreads();

        {   // reduce chunks (fixed order) + fp64 sigmoid + bias
            #pragma unroll
            for (int j = 0; j < 2; ++j) {
                const double sum = ((Part[0][j][tid] + Part[1][j][tid]) + Part[2][j][tid]) + Part[3][j][tid];
                Sd[j][tid] = 1.0 / (1.0 + exp(-sum)) + (double)bias[tid];
            }
        }
        __syncthreads();

        if (tid < nt) {
            double* row = Sd[tid];

            double gs[NGROUP];
            for (int g = 0; g < NGROUP; ++g) {
                const int b0 = g * GSIZE;
                double m1 = -1e300, m2 = -1e300;
                for (int j = 0; j < GSIZE; ++j) {
                    const double v = row[b0 + j];
                    if (v > m1) { m2 = m1; m1 = v; }
                    else if (v > m2) { m2 = v; }
                }
                gs[g] = m1 + m2;
            }

            unsigned gsel = 0;
            for (int g = 0; g < NGROUP; ++g) {
                int rank = 0;
                for (int h = 0; h < NGROUP; ++h)
                    rank += (gs[h] > gs[g]) || (gs[h] == gs[g] && h < g);
                if (rank < TOPG) gsel |= 1u << g;
            }

            double wk[TOPK];
            int    ik[TOPK];
            double wsum = 0.0;
            for (int k = 0; k < TOPK; ++k) {
                double bv = -1e300;
                int    bi = 0;
                for (int g = 0; g < NGROUP; ++g) {
                    if (!((gsel >> g) & 1u)) continue;
                    const int b0 = g * GSIZE;
                    for (int j = 0; j < GSIZE; ++j) {
                        const int e = b0 + j;
                        if (row[e] > bv) { bv = row[e]; bi = e; }
                    }
                }
                const double wv = bv - (double)bias[bi];
                wk[k] = wv; ik[k] = bi; wsum += wv;
                row[bi] = -1e300;
            }

            const double norm = SCALE / wsum;
            const int t = ws[RLIST_OFF + base + tid];
            float* oi = out + (size_t)t * TOPK;
            float* ow = out + (size_t)T_TOKENS * TOPK + (size_t)t * TOPK;
            for (int k = 0; k < TOPK; ++k) {
                oi[k] = (float)ik[k];
                ow[k] = (float)(wk[k] * norm);
            }
        }
    }
}

extern "C" void kernel_launch(void* const* d_in, const int* in_sizes, int n_in,
                              void* d_out, int out_size, void* d_ws, size_t ws_size,
                              hipStream_t stream) {
    const float* H    = (const float*)d_in[0];
    const float* Wt   = (const float*)d_in[1];
    const float* bias = (const float*)d_in[2];
    float* out = (float*)d_out;
    int*   ws  = (int*)d_ws;
    unsigned short* wp = (unsigned short*)((char*)d_ws + WPACK_OFF_BYTES);

    zero_counter<<<1, 64, 0, stream>>>(ws);
    pack_w_kernel<<<256, 256, 0, stream>>>(Wt, wp);
    router_main<<<T_TOKENS / BM, 256, 0, stream>>>(H, bias, wp, out, ws);
    router_rescue<<<512, 256, 0, stream>>>(H, Wt, bias, out, ws);
}

// Round 7
// 273.989 us; speedup vs baseline: 6.7699x; 1.0269x over previous
//
#include <hip/hip_runtime.h>
#include <math.h>

// Problem constants
#define T_TOKENS 32768
#define DIM      2048
#define NEXP     256
#define NGROUP   8
#define GSIZE    32
#define TOPG     4
#define TOPK     8
#define SCALE    2.5
#define TAU      2e-5f     // rescue margin; 3-term bf16-split err sigma ~4e-7

// Main-pass tiling
#define BM  64
#define NIT 32             // iterations of 64-k (2 sub-steps of 32)
#define SC_STRIDE 257

#define RLIST_OFF 16                 // ints; ws[0] = counter
#define WPACK_OFF_BYTES (1 << 18)    // 256 KiB into d_ws

typedef __attribute__((ext_vector_type(8))) short bf16x8;
typedef __attribute__((ext_vector_type(8))) unsigned short u16x8;
typedef __attribute__((ext_vector_type(4))) float f32x4;

__device__ __forceinline__ unsigned short f2bf_rne(float f) {
    unsigned u = __float_as_uint(f);
    u += 0x7fffu + ((u >> 16) & 1u);
    return (unsigned short)(u >> 16);
}
__device__ __forceinline__ float bf2f(unsigned short h) {
    return __uint_as_float(((unsigned)h) << 16);
}

// ------------------------------------------------------------- pack W ----
// Wpack slot (s, n, h, lane) holds 8 bf16: W[e=16n+(lane&15)][k=32s+(lane>>4)*8+i]
__global__ void pack_w_kernel(const float* __restrict__ Wt,
                              unsigned short* __restrict__ wp,
                              int* __restrict__ ws) {
    if (blockIdx.x == 0 && threadIdx.x == 0) ws[0] = 0;   // rescue counter
    const int slot = blockIdx.x * 256 + threadIdx.x;      // 0..65535
    const int lane = slot & 63;
    const int n    = (slot >> 6) & 15;
    const int s    = slot >> 10;
    const int e    = n * 16 + (lane & 15);
    const int k0   = s * 32 + (lane >> 4) * 8;
    const float* src = Wt + (size_t)e * DIM + k0;
    const float4 v0 = *(const float4*)src;
    const float4 v1 = *(const float4*)(src + 4);
    const float a[8] = {v0.x, v0.y, v0.z, v0.w, v1.x, v1.y, v1.z, v1.w};
    union { unsigned short u[8]; u16x8 v; } uh, ul;
    #pragma unroll
    for (int i = 0; i < 8; ++i) {
        const unsigned short hb = f2bf_rne(a[i]);
        uh.u[i] = hb;
        ul.u[i] = f2bf_rne(a[i] - bf2f(hb));
    }
    const size_t base = ((size_t)(s * 16 + n) * 2) * 64 + lane;
    *(u16x8*)(wp + base * 8)        = uh.v;   // hi
    *(u16x8*)(wp + (base + 64) * 8) = ul.v;   // lo
}

// ---------------------------------------------------------------- main ----
// 512 threads = 8 waves; wave w owns 4 M-tiles x 2 N-tiles (2w, 2w+1).
// Grid 512 -> 2 blocks/CU -> 16 waves/CU = 4 waves/SIMD.
__global__ __launch_bounds__(512, 4) void router_main(
    const float* __restrict__ H,
    const float* __restrict__ bias,
    const unsigned short* __restrict__ wp,
    float* __restrict__ out,
    int* __restrict__ ws)
{
    // union: Ahl dbuf (32 KiB) / Sc (65792 B)
    __shared__ __align__(16) char smraw[BM * SC_STRIDE * 4];
    __shared__ float biasS[NEXP];

    typedef unsigned short AhlBuf[2][2][4][64][8];   // [sub][h][m][lane][i]
    AhlBuf* Ahl = reinterpret_cast<AhlBuf*>(smraw);  // Ahl[buf]
    float*  Sc  = reinterpret_cast<float*>(smraw);

    const int tid  = threadIdx.x;
    const int lane = tid & 63;
    const int w    = tid >> 6;           // wave 0..7
    const int t0   = blockIdx.x * BM;

    if (tid < NEXP) biasS[tid] = bias[tid];

    f32x4 acc[4][2];   // [m][jj], expert tile = 2w+jj
    #pragma unroll
    for (int m = 0; m < 4; ++m)
        #pragma unroll
        for (int jj = 0; jj < 2; ++jj)
            acc[m][jj] = (f32x4){0.f, 0.f, 0.f, 0.f};

    // A staging mapping: 512 threads cover 64 rows x 8 k-octets (64 k per iter)
    const int arow = tid >> 3;           // 0..63
    const int koct = tid & 7;            // 0..7
    const int sub  = koct >> 2;          // which 32-k half
    const int kq   = koct & 3;
    const int am   = arow >> 4;
    const int lw   = (kq << 4) | (arow & 15);
    const float* Aptr = H + (size_t)(t0 + arow) * DIM + koct * 8;

    auto loadH = [&](int it, float4& x0, float4& x1) {
        const float* p = Aptr + (size_t)it * 64;
        x0 = *(const float4*)p;
        x1 = *(const float4*)(p + 4);
    };
    auto stageIter = [&](int b, const float4& x0, const float4& x1) {
        const float a[8] = {x0.x, x0.y, x0.z, x0.w, x1.x, x1.y, x1.z, x1.w};
        union { unsigned short u[8]; u16x8 v; } uh, ul;
        #pragma unroll
        for (int i = 0; i < 8; ++i) {
            const unsigned short hb = f2bf_rne(a[i]);
            uh.u[i] = hb;
            ul.u[i] = f2bf_rne(a[i] - bf2f(hb));
        }
        *(u16x8*)&Ahl[b][sub][0][am][lw][0] = uh.v;
        *(u16x8*)&Ahl[b][sub][1][am][lw][0] = ul.v;
    };
    auto loadB = [&](int s, bf16x8 (&Bh)[2], bf16x8 (&Bl)[2]) {
        #pragma unroll
        for (int jj = 0; jj < 2; ++jj) {
            const size_t slot = ((size_t)(s * 16 + 2 * w + jj) * 2) * 64 + lane;
            Bh[jj] = *(const bf16x8*)(wp + slot * 8);
            Bl[jj] = *(const bf16x8*)(wp + (slot + 64) * 8);
        }
    };
    auto computeSub = [&](int b, int ss, bf16x8 (&Bh)[2], bf16x8 (&Bl)[2]) {
        bf16x8 Ah[4], Al[4];
        #pragma unroll
        for (int m = 0; m < 4; ++m) {
            Ah[m] = *(const bf16x8*)&Ahl[b][ss][0][m][lane][0];
            Al[m] = *(const bf16x8*)&Ahl[b][ss][1][m][lane][0];
        }
        #pragma unroll
        for (int m = 0; m < 4; ++m)
            #pragma unroll
            for (int jj = 0; jj < 2; ++jj) {
                acc[m][jj] = __builtin_amdgcn_mfma_f32_16x16x32_bf16(Al[m], Bh[jj], acc[m][jj], 0, 0, 0);
                acc[m][jj] = __builtin_amdgcn_mfma_f32_16x16x32_bf16(Ah[m], Bl[jj], acc[m][jj], 0, 0, 0);
                acc[m][jj] = __builtin_amdgcn_mfma_f32_16x16x32_bf16(Ah[m], Bh[jj], acc[m][jj], 0, 0, 0);
            }
    };

    bf16x8 Ba_h[2], Ba_l[2], Bb_h[2], Bb_l[2];
    float4 hS0, hS1, hL0, hL1;

    // prologue: stage iter 0 into buf0, prefetch h(1), B(sub 0)
    {
        float4 c0, c1;
        loadH(0, c0, c1);
        stageIter(0, c0, c1);
    }
    loadH(1, hS0, hS1);
    loadB(0, Ba_h, Ba_l);
    __syncthreads();

    for (int it = 0; it < NIT; it += 2) {
        // ---- iter it: compute buf0 (subs 2it,2it+1); stage buf1 = A(it+1) ----
        loadH(min(it + 2, NIT - 1), hL0, hL1);
        stageIter(1, hS0, hS1);
        loadB(2 * it + 1, Bb_h, Bb_l);
        computeSub(0, 0, Ba_h, Ba_l);
        loadB(min(2 * it + 2, 2 * NIT - 1), Ba_h, Ba_l);
        computeSub(0, 1, Bb_h, Bb_l);
        __syncthreads();

        // ---- iter it+1: compute buf1; stage buf0 = A(it+2) ----
        loadH(min(it + 3, NIT - 1), hS0, hS1);
        if (it + 2 < NIT) stageIter(0, hL0, hL1);
        loadB(min(2 * it + 3, 2 * NIT - 1), Bb_h, Bb_l);
        computeSub(1, 0, Ba_h, Ba_l);
        loadB(min(2 * it + 4, 2 * NIT - 1), Ba_h, Ba_l);
        computeSub(1, 1, Bb_h, Bb_l);
        __syncthreads();
    }

    // ---- epilogue: biased sigmoid -> Sc ----
    const int rbase = (lane >> 4) * 4;
    const int cc    = lane & 15;
    #pragma unroll
    for (int m = 0; m < 4; ++m)
        #pragma unroll
        for (int jj = 0; jj < 2; ++jj)
            #pragma unroll
            for (int r = 0; r < 4; ++r) {
                const int token  = 16 * m + rbase + r;
                const int expert = 16 * (2 * w + jj) + cc;
                const float sg = 1.0f / (1.0f + expf(-acc[m][jj][r]));
                Sc[token * SC_STRIDE + expert] = sg + biasS[expert];
            }
    __syncthreads();

    // ---- routing (fp32) + margin check (round-4/5/6 proven) ----
    if (tid < BM) {
        float* row = &Sc[tid * SC_STRIDE];

        float gs[NGROUP];
        for (int g = 0; g < NGROUP; ++g) {
            const int base = g * GSIZE;
            float m1 = -3e38f, m2 = -3e38f;
            for (int j = 0; j < GSIZE; ++j) {
                const float v = row[base + j];
                if (v > m1) { m2 = m1; m1 = v; }
                else if (v > m2) { m2 = v; }
            }
            gs[g] = m1 + m2;
        }

        unsigned gsel = 0;
        float minSel = 3e38f, maxUn = -3e38f;
        #pragma unroll
        for (int g = 0; g < NGROUP; ++g) {
            int rank = 0;
            #pragma unroll
            for (int h = 0; h < NGROUP; ++h)
                rank += (gs[h] > gs[g]) || (gs[h] == gs[g] && h < g);
            if (rank < TOPG) { gsel |= 1u << g; minSel = fminf(minSel, gs[g]); }
            else             { maxUn = fmaxf(maxUn, gs[g]); }
        }
        float minMargin = minSel - maxUn;

        float wk[TOPK];
        int   ik[TOPK];
        float wsum = 0.0f;
        float prev = 3e38f;
        #pragma unroll
        for (int k = 0; k < TOPK + 1; ++k) {
            float bv = -3e38f;
            int   bi = 0;
            for (int g = 0; g < NGROUP; ++g) {
                if (!((gsel >> g) & 1u)) continue;
                const int base = g * GSIZE;
                for (int j = 0; j < GSIZE; ++j) {
                    const int e = base + j;
                    const float v = row[e];
                    if (v > bv) { bv = v; bi = e; }
                }
            }
            if (k > 0) minMargin = fminf(minMargin, prev - bv);
            prev = bv;
            if (k < TOPK) {
                const float wv = bv - biasS[bi];
                wk[k] = wv; ik[k] = bi; wsum += wv;
                row[bi] = -3e38f;
            }
        }

        const float norm = (float)SCALE / wsum;
        const size_t t = (size_t)(t0 + tid);
        float* oi = out + t * TOPK;
        float* ow = out + (size_t)T_TOKENS * TOPK + t * TOPK;
        #pragma unroll
        for (int k = 0; k < TOPK; ++k) {
            oi[k] = (float)ik[k];
            ow[k] = wk[k] * norm;
        }

        if (minMargin < TAU) {
            const int r = atomicAdd(ws, 1);
            ws[RLIST_OFF + r] = t0 + tid;
        }
    }
}

// -------------------------------------------------------------- rescue ----
// 2 tokens per block-iteration; threads = 64 experts x 4 k-chunks; exact fp64.
__global__ __launch_bounds__(256) void router_rescue(
    const float* __restrict__ H,
    const float* __restrict__ Wt,
    const float* __restrict__ bias,
    float* __restrict__ out,
    const int* __restrict__ ws)
{
    __shared__ float  Hs[2][DIM];          // 16 KiB
    __shared__ double Part[4][2][NEXP];    // 16 KiB
    __shared__ double Sd[2][NEXP];         //  4 KiB

    const int tid = threadIdx.x;
    const int nR  = ws[0];
    const int e0  = tid & 63;
    const int kc  = tid >> 6;              // 0..3

    for (int base = blockIdx.x * 2; base < nR; base += gridDim.x * 2) {
        const int nt = min(2, nR - base);
        __syncthreads();

        for (int j = 0; j < nt; ++j) {
            const int t = ws[RLIST_OFF + base + j];
            const float* hp = H + (size_t)t * DIM + tid * 8;
            const float4 a = *(const float4*)hp;
            const float4 b = *(const float4*)(hp + 4);
            float* d = &Hs[j][tid * 8];
            d[0] = a.x; d[1] = a.y; d[2] = a.z; d[3] = a.w;
            d[4] = b.x; d[5] = b.y; d[6] = b.z; d[7] = b.w;
        }
        __syncthreads();

        #pragma unroll
        for (int q = 0; q < 4; ++q) {
            const int e = e0 + 64 * q;
            const float* wr  = Wt + (size_t)e * DIM + kc * 512;
            const float* h0p = &Hs[0][kc * 512];
            const float* h1p = &Hs[1][kc * 512];
            double a00 = 0.0, a01 = 0.0, a10 = 0.0, a11 = 0.0;   // 4 indep chains
            for (int k = 0; k < 512; k += 8) {
                const float4 w0 = *(const float4*)(wr + k);
                const float4 w1 = *(const float4*)(wr + k + 4);
                a00 = fma((double)h0p[k + 0], (double)w0.x, a00);
                a00 = fma((double)h0p[k + 1], (double)w0.y, a00);
                a00 = fma((double)h0p[k + 2], (double)w0.z, a00);
                a00 = fma((double)h0p[k + 3], (double)w0.w, a00);
                a01 = fma((double)h0p[k + 4], (double)w1.x, a01);
                a01 = fma((double)h0p[k + 5], (double)w1.y, a01);
                a01 = fma((double)h0p[k + 6], (double)w1.z, a01);
                a01 = fma((double)h0p[k + 7], (double)w1.w, a01);
                a10 = fma((double)h1p[k + 0], (double)w0.x, a10);
                a10 = fma((double)h1p[k + 1], (double)w0.y, a10);
                a10 = fma((double)h1p[k + 2], (double)w0.z, a10);
                a10 = fma((double)h1p[k + 3], (double)w0.w, a10);
                a11 = fma((double)h1p[k + 4], (double)w1.x, a11);
                a11 = fma((double)h1p[k + 5], (double)w1.y, a11);
                a11 = fma((double)h1p[k + 6], (double)w1.z, a11);
                a11 = fma((double)h1p[k + 7], (double)w1.w, a11);
            }
            Part[kc][0][e] = a00 + a01;
            Part[kc][1][e] = a10 + a11;
        }
        __syncthreads();

        {   // reduce chunks (fixed order) + fp64 sigmoid + bias
            #pragma unroll
            for (int j = 0; j < 2; ++j) {
                const double sum = ((Part[0][j][tid] + Part[1][j][tid]) + Part[2][j][tid]) + Part[3][j][tid];
                Sd[j][tid] = 1.0 / (1.0 + exp(-sum)) + (double)bias[tid];
            }
        }
        __syncthreads();

        if (tid < nt) {
            double* row = Sd[tid];

            double gs[NGROUP];
            for (int g = 0; g < NGROUP; ++g) {
                const int b0 = g * GSIZE;
                double m1 = -1e300, m2 = -1e300;
                for (int j = 0; j < GSIZE; ++j) {
                    const double v = row[b0 + j];
                    if (v > m1) { m2 = m1; m1 = v; }
                    else if (v > m2) { m2 = v; }
                }
                gs[g] = m1 + m2;
            }

            unsigned gsel = 0;
            for (int g = 0; g < NGROUP; ++g) {
                int rank = 0;
                for (int h = 0; h < NGROUP; ++h)
                    rank += (gs[h] > gs[g]) || (gs[h] == gs[g] && h < g);
                if (rank < TOPG) gsel |= 1u << g;
            }

            double wk[TOPK];
            int    ik[TOPK];
            double wsum = 0.0;
            for (int k = 0; k < TOPK; ++k) {
                double bv = -1e300;
                int    bi = 0;
                for (int g = 0; g < NGROUP; ++g) {
                    if (!((gsel >> g) & 1u)) continue;
                    const int b0 = g * GSIZE;
                    for (int j = 0; j < GSIZE; ++j) {
                        const int e = b0 + j;
                        if (row[e] > bv) { bv = row[e]; bi = e; }
                    }
                }
                const double wv = bv - (double)bias[bi];
                wk[k] = wv; ik[k] = bi; wsum += wv;
                row[bi] = -1e300;
            }

            const double norm = SCALE / wsum;
            const int t = ws[RLIST_OFF + base + tid];
            float* oi = out + (size_t)t * TOPK;
            float* ow = out + (size_t)T_TOKENS * TOPK + (size_t)t * TOPK;
            for (int k = 0; k < TOPK; ++k) {
                oi[k] = (float)ik[k];
                ow[k] = (float)(wk[k] * norm);
            }
        }
    }
}

extern "C" void kernel_launch(void* const* d_in, const int* in_sizes, int n_in,
                              void* d_out, int out_size, void* d_ws, size_t ws_size,
                              hipStream_t stream) {
    const float* H    = (const float*)d_in[0];
    const float* Wt   = (const float*)d_in[1];
    const float* bias = (const float*)d_in[2];
    float* out = (float*)d_out;
    int*   ws  = (int*)d_ws;
    unsigned short* wp = (unsigned short*)((char*)d_ws + WPACK_OFF_BYTES);

    pack_w_kernel<<<256, 256, 0, stream>>>(Wt, wp, ws);
    router_main<<<T_TOKENS / BM, 512, 0, stream>>>(H, bias, wp, out, ws);
    router_rescue<<<512, 256, 0, stream>>>(H, Wt, bias, out, ws);
}